// Round 5
// baseline (452.364 us; speedup 1.0000x reference)
//
#include <hip/hip_runtime.h>
#include <math.h>

#define NN 50000
#define EE 800000
#define HH 4
#define CC 64
#define DE 16
#define GG 64
#define HC 256          // H*C
#define NEG 0.2f
#define EPSV 1e-5f
#define NB 196          // scan blocks: 196*256 = 50176 >= NN

__device__ __forceinline__ unsigned short f2bf(float f) {
  unsigned int x = __float_as_uint(f);
  unsigned int r = (x + 0x7fff + ((x >> 16) & 1)) >> 16;  // round-nearest-even
  return (unsigned short)r;
}
__device__ __forceinline__ float lrelu(float a) {
  return fmaxf(a, 0.f) + NEG * fminf(a, 0.f);
}

// K0: fold attention vectors through the projections.
__global__ __launch_bounds__(256) void k_prep(
    const float* __restrict__ W, const float* __restrict__ We,
    const float* __restrict__ as_, const float* __restrict__ ad_,
    const float* __restrict__ ae_,
    float* __restrict__ u_src, float* __restrict__ u_dst,
    float* __restrict__ v_edge) {
  int t = threadIdx.x;
  int k = t >> 2, h = t & 3;
  float s1 = 0.f, s2 = 0.f;
  for (int c = 0; c < CC; ++c) {
    float w = W[k * HC + h * CC + c];
    s1 += w * as_[h * CC + c];
    s2 += w * ad_[h * CC + c];
  }
  u_src[t] = s1;
  u_dst[t] = s2;
  if (t < DE * HH) {
    int d = t >> 2, hh = t & 3;
    float s3 = 0.f;
    for (int c = 0; c < CC; ++c) s3 += We[d * HC + hh * CC + c] * ae_[hh * CC + c];
    v_edge[t] = s3;
  }
}

// K1: x16[n][c][h] = bf16 of x[n][h][c]  (TRANSPOSED so k_gat reads one
// ushort4 per lane). LDS transpose per node row.
__global__ __launch_bounds__(256) void k_xproj(
    const float* __restrict__ node, const float* __restrict__ W,
    unsigned short* __restrict__ x16) {
  __shared__ unsigned short tile[HC];
  int lane = threadIdx.x & 63;   // = c
  int wid = threadIdx.x >> 6;    // = h
  int t = threadIdx.x;
  float wcol[CC];
#pragma unroll
  for (int k = 0; k < CC; ++k) wcol[k] = W[k * HC + wid * 64 + lane];
  for (int n = blockIdx.x; n < NN; n += gridDim.x) {
    float nval = node[n * CC + lane];
    float acc = 0.f;
#pragma unroll
    for (int k = 0; k < CC; ++k) {
      float s = __uint_as_float(__builtin_amdgcn_readlane(__float_as_uint(nval), k));
      acc += s * wcol[k];
    }
    tile[lane * 4 + wid] = f2bf(acc);   // [c][h]
    __syncthreads();
    x16[(size_t)n * HC + t] = tile[t];
    __syncthreads();
  }
}

// K1b: per-node attention logits via the folded u mats.
__global__ __launch_bounds__(256) void k_attn_node(
    const float* __restrict__ node, const float* __restrict__ u_src,
    const float* __restrict__ u_dst, float* __restrict__ a_src,
    float* __restrict__ a_dst) {
  __shared__ float us[HC], ud[HC];
  int t = threadIdx.x;
  us[t] = u_src[t];
  ud[t] = u_dst[t];
  __syncthreads();
  int n = blockIdx.x * 256 + t;
  if (n >= NN) return;
  const float4* n4 = (const float4*)(node + n * CC);
  float aS[4] = {0, 0, 0, 0}, aD[4] = {0, 0, 0, 0};
#pragma unroll
  for (int kk = 0; kk < 16; ++kk) {
    float4 nv = n4[kk];
    float nvs[4] = {nv.x, nv.y, nv.z, nv.w};
#pragma unroll
    for (int j = 0; j < 4; ++j) {
      int k = kk * 4 + j;
#pragma unroll
      for (int h = 0; h < 4; ++h) {
        aS[h] += nvs[j] * us[k * 4 + h];
        aD[h] += nvs[j] * ud[k * 4 + h];
      }
    }
  }
  *(float4*)(a_src + n * 4) = make_float4(aS[0], aS[1], aS[2], aS[3]);
  *(float4*)(a_dst + n * 4) = make_float4(aD[0], aD[1], aD[2], aD[3]);
}

// K2: dst histogram only.
__global__ __launch_bounds__(256) void k_hist(
    const int* __restrict__ ei, int* __restrict__ hist) {
  int e = blockIdx.x * 256 + threadIdx.x;
  if (e >= EE) return;
  atomicAdd(&hist[ei[EE + e]], 1);
}

// K3a: coalesced per-block sums of the histogram.
__global__ __launch_bounds__(256) void k_scanA(
    const int* __restrict__ hist, int* __restrict__ bsum) {
  __shared__ int s[256];
  int t = threadIdx.x;
  int idx = blockIdx.x * 256 + t;
  s[t] = (idx < NN) ? hist[idx] : 0;
  __syncthreads();
  for (int d = 128; d; d >>= 1) {
    if (t < d) s[t] += s[t + d];
    __syncthreads();
  }
  if (t == 0) bsum[blockIdx.x] = s[0];
}

// K3b: single block: exclusive scan of NB block sums.
__global__ __launch_bounds__(256) void k_scanB(
    const int* __restrict__ bsum, int* __restrict__ boff,
    int* __restrict__ ptr) {
  __shared__ int s[256];
  int t = threadIdx.x;
  int v = (t < NB) ? bsum[t] : 0;
  s[t] = v;
  __syncthreads();
  for (int d = 1; d < 256; d <<= 1) {
    int u = (t >= d) ? s[t - d] : 0;
    __syncthreads();
    s[t] += u;
    __syncthreads();
  }
  if (t < NB) boff[t] = s[t] - v;
  if (t == 255) ptr[NN] = s[255];
}

// K3c: per-block exclusive scan + block offset -> ptr, cursor.
__global__ __launch_bounds__(256) void k_scanC(
    const int* __restrict__ hist, const int* __restrict__ boff,
    int* __restrict__ ptr, int* __restrict__ cursor) {
  __shared__ int s[256];
  int t = threadIdx.x;
  int idx = blockIdx.x * 256 + t;
  int v = (idx < NN) ? hist[idx] : 0;
  s[t] = v;
  __syncthreads();
  for (int d = 1; d < 256; d <<= 1) {
    int u = (t >= d) ? s[t - d] : 0;
    __syncthreads();
    s[t] += u;
    __syncthreads();
  }
  if (idx < NN) {
    int p = boff[blockIdx.x] + s[t] - v;
    ptr[idx] = p;
    cursor[idx] = p;
  }
}

// K4: fused edge pass: compute t = exp(lrelu(a_src[sn]+a_dst[dn]+edge_attr@v))
// lane-parallel, scatter {t, sn, e} into dst-sorted slots. No `partial` array.
__global__ __launch_bounds__(256) void k_edge_perm(
    const float* __restrict__ edge_attr, const int* __restrict__ ei,
    const float* __restrict__ a_src, const float* __restrict__ a_dst,
    const float* __restrict__ v_edge, int* __restrict__ cursor,
    float* __restrict__ esort, int* __restrict__ ssort,
    int* __restrict__ eid) {
  __shared__ float vs[DE * HH];
  int t = threadIdx.x;
  if (t < DE * HH) vs[t] = v_edge[t];
  __syncthreads();
  int e = blockIdx.x * 256 + t;
  if (e >= EE) return;
  const float4* ea4 = (const float4*)(edge_attr + (size_t)e * DE);
  float ae[4] = {0, 0, 0, 0};
#pragma unroll
  for (int dd = 0; dd < 4; ++dd) {
    float4 ev = ea4[dd];
    float evs[4] = {ev.x, ev.y, ev.z, ev.w};
#pragma unroll
    for (int j = 0; j < 4; ++j) {
      int d = dd * 4 + j;
#pragma unroll
      for (int h = 0; h < 4; ++h) ae[h] += evs[j] * vs[d * 4 + h];
    }
  }
  int sn = ei[e], dn = ei[EE + e];
  float4 as4 = *(const float4*)(a_src + (size_t)sn * 4);
  float4 ad4 = *(const float4*)(a_dst + (size_t)dn * 4);
  float t0 = __expf(lrelu(as4.x + ad4.x + ae[0]));
  float t1 = __expf(lrelu(as4.y + ad4.y + ae[1]));
  float t2 = __expf(lrelu(as4.z + ad4.z + ae[2]));
  float t3 = __expf(lrelu(as4.w + ad4.w + ae[3]));
  int pos = atomicAdd(&cursor[dn], 1);
  eid[pos] = e;
  ssort[pos] = sn;
  *(float4*)(esort + (size_t)pos * 4) = make_float4(t0, t1, t2, t3);
}

// K5: one wave per dst node. Main loop per edge: broadcast-load t4, one
// 8B/lane x16 load, 4 FMAs, 4 denom adds. exp already hoisted to k_edge_perm.
__global__ __launch_bounds__(256) void k_gat(
    const int* __restrict__ ptr, const int* __restrict__ eid,
    const int* __restrict__ ssort, const float* __restrict__ esort,
    const unsigned short* __restrict__ x16, float* __restrict__ out_acc,
    float* __restrict__ att_out) {
  int lane = threadIdx.x & 63;
  int w = threadIdx.x >> 6;
  int v = blockIdx.x * 4 + w;
  int start = ptr[v], end = ptr[v + 1];
  float d0 = 0.f, d1 = 0.f, d2 = 0.f, d3 = 0.f;
  float acc0 = 0.f, acc1 = 0.f, acc2 = 0.f, acc3 = 0.f;
#pragma unroll 2
  for (int j = start; j < end; ++j) {
    float4 tv = *(const float4*)(esort + (size_t)j * 4);  // wave-uniform bcast
    int sn = ssort[j];
    uint2 u = *(const uint2*)(x16 + (size_t)sn * HC + lane * 4);
    d0 += tv.x; d1 += tv.y; d2 += tv.z; d3 += tv.w;
    float x0 = __uint_as_float(u.x << 16);
    float x1 = __uint_as_float(u.x & 0xffff0000u);
    float x2 = __uint_as_float(u.y << 16);
    float x3 = __uint_as_float(u.y & 0xffff0000u);
    acc0 += tv.x * x0;
    acc1 += tv.y * x1;
    acc2 += tv.z * x2;
    acc3 += tv.w * x3;
  }
  float r0 = 1.f / (d0 + 1e-16f), r1 = 1.f / (d1 + 1e-16f);
  float r2 = 1.f / (d2 + 1e-16f), r3 = 1.f / (d3 + 1e-16f);
  out_acc[(size_t)v * CC + lane] =
      0.25f * (r0 * acc0 + r1 * acc1 + r2 * acc2 + r3 * acc3);
  // att output, lane-parallel over the run
  for (int j = start + lane; j < end; j += 64) {
    float4 tv = *(const float4*)(esort + (size_t)j * 4);
    *(float4*)(att_out + (size_t)eid[j] * 4) =
        make_float4(tv.x * r0, tv.y * r1, tv.z * r2, tv.w * r3);
  }
}

// K6: GraphNorm stats, one block per group.
__global__ __launch_bounds__(256) void k_stats(
    const int* __restrict__ batch, const float* __restrict__ out_acc,
    const float* __restrict__ bias, const float* __restrict__ gns,
    float* __restrict__ mean_s, float* __restrict__ istd) {
  int g = blockIdx.x;
  int lane = threadIdx.x & 63;
  int w = threadIdx.x >> 6;
  int lo = 0, hi = NN;
  while (lo < hi) {
    int mid = (lo + hi) >> 1;
    if (batch[mid] < g) lo = mid + 1; else hi = mid;
  }
  int start = lo;
  hi = NN;
  while (lo < hi) {
    int mid = (lo + hi) >> 1;
    if (batch[mid] < g + 1) lo = mid + 1; else hi = mid;
  }
  int end = lo;
  float b = bias[lane];
  float s1 = 0.f, s2 = 0.f;
  for (int n = start + w; n < end; n += 4) {
    float v = out_acc[(size_t)n * CC + lane] + b;
    s1 += v;
    s2 += v * v;
  }
  __shared__ float l1[4][64], l2[4][64];
  l1[w][lane] = s1;
  l2[w][lane] = s2;
  __syncthreads();
  if (w == 0) {
    s1 = l1[0][lane] + l1[1][lane] + l1[2][lane] + l1[3][lane];
    s2 = l2[0][lane] + l2[1][lane] + l2[2][lane] + l2[3][lane];
    float c = fmaxf((float)(end - start), 1.0f);
    float mean = s1 / c;
    float ms = mean * gns[lane];
    float var = s2 / c - 2.f * ms * mean + ms * ms;
    mean_s[g * CC + lane] = ms;
    istd[g * CC + lane] = rsqrtf(var + EPSV);
  }
}

// K7: normalize + affine + relu -> y
__global__ __launch_bounds__(256) void k_final(
    const int* __restrict__ batch, const float* __restrict__ out_acc,
    const float* __restrict__ bias, const float* __restrict__ mean_s,
    const float* __restrict__ istd, const float* __restrict__ gnw,
    const float* __restrict__ gnb, float* __restrict__ y) {
  int lane = threadIdx.x & 63;
  int n = blockIdx.x * 4 + (threadIdx.x >> 6);
  int g = batch[n];
  float v = out_acc[(size_t)n * CC + lane] + bias[lane];
  float o = (v - mean_s[g * CC + lane]) * istd[g * CC + lane];
  float r = gnw[lane] * o + gnb[lane];
  y[(size_t)n * CC + lane] = fmaxf(r, 0.0f);
}

extern "C" void kernel_launch(void* const* d_in, const int* in_sizes, int n_in,
                              void* d_out, int out_size, void* d_ws, size_t ws_size,
                              hipStream_t stream) {
  const float* node = (const float*)d_in[0];
  const int* ei = (const int*)d_in[1];
  const float* eatt = (const float*)d_in[2];
  const int* batch = (const int*)d_in[3];
  const float* W = (const float*)d_in[4];
  const float* We = (const float*)d_in[5];
  const float* att_src = (const float*)d_in[6];
  const float* att_dst = (const float*)d_in[7];
  const float* att_edge = (const float*)d_in[8];
  const float* bias = (const float*)d_in[9];
  const float* gnw = (const float*)d_in[10];
  const float* gnb = (const float*)d_in[11];
  const float* gns = (const float*)d_in[12];

  float* ws = (float*)d_ws;
  size_t off = 0;
  float* esort = ws + off;    off += (size_t)EE * HH;   // 3.2M floats
  float* a_src = ws + off;    off += (size_t)NN * HH;
  float* a_dst = ws + off;    off += (size_t)NN * HH;
  float* u_src = ws + off;    off += HC;
  float* u_dst = ws + off;    off += HC;
  float* v_edge = ws + off;   off += 64;
  float* mean_s = ws + off;   off += GG * CC;
  float* istd = ws + off;     off += GG * CC;
  float* out_acc = ws + off;  off += (size_t)NN * CC;
  unsigned short* x16 = (unsigned short*)(ws + off);
  off += (size_t)NN * HC / 2;                           // 12.8M ushort
  int* iws = (int*)(ws + off);
  size_t ioff = 0;
  int* hist = iws + ioff;     ioff += NN;
  int* ptr = iws + ioff;      ioff += NN + 1;
  int* cursor = iws + ioff;   ioff += NN;
  int* eid = iws + ioff;      ioff += EE;
  int* ssort = iws + ioff;    ioff += EE;
  int* bsum = iws + ioff;     ioff += NB;
  int* boff = iws + ioff;     ioff += NB;

  hipMemsetAsync(hist, 0, NN * sizeof(int), stream);

  float* y_out = (float*)d_out;
  float* att_out = (float*)d_out + (size_t)NN * CC;

  k_prep<<<1, 256, 0, stream>>>(W, We, att_src, att_dst, att_edge, u_src, u_dst,
                                v_edge);
  k_attn_node<<<(NN + 255) / 256, 256, 0, stream>>>(node, u_src, u_dst, a_src,
                                                    a_dst);
  k_hist<<<(EE + 255) / 256, 256, 0, stream>>>(ei, hist);
  k_xproj<<<2048, 256, 0, stream>>>(node, W, x16);
  k_scanA<<<NB, 256, 0, stream>>>(hist, bsum);
  k_scanB<<<1, 256, 0, stream>>>(bsum, boff, ptr);
  k_scanC<<<NB, 256, 0, stream>>>(hist, boff, ptr, cursor);
  k_edge_perm<<<(EE + 255) / 256, 256, 0, stream>>>(eatt, ei, a_src, a_dst,
                                                    v_edge, cursor, esort,
                                                    ssort, eid);
  k_gat<<<NN / 4, 256, 0, stream>>>(ptr, eid, ssort, esort, x16, out_acc,
                                    att_out);
  k_stats<<<GG, 256, 0, stream>>>(batch, out_acc, bias, gns, mean_s, istd);
  k_final<<<NN / 4, 256, 0, stream>>>(batch, out_acc, bias, mean_s, istd, gnw,
                                      gnb, y_out);
}

// Round 6
// 420.590 us; speedup vs baseline: 1.0755x; 1.0755x over previous
//
#include <hip/hip_runtime.h>
#include <math.h>

#define NN 50000
#define EE 800000
#define HH 4
#define CC 64
#define DE 16
#define GG 64
#define HC 256          // H*C
#define NEG 0.2f
#define EPSV 1e-5f
#define NB 196          // scan blocks: 196*256 = 50176 >= NN

__device__ __forceinline__ unsigned short f2bf(float f) {
  unsigned int x = __float_as_uint(f);
  unsigned int r = (x + 0x7fff + ((x >> 16) & 1)) >> 16;  // round-nearest-even
  return (unsigned short)r;
}
__device__ __forceinline__ float lrelu(float a) {
  return fmaxf(a, 0.f) + NEG * fminf(a, 0.f);
}

// K0: fold att_edge through W_edge: v_edge[d][h] (layout [d*4+h]).
__global__ __launch_bounds__(64) void k_prep(
    const float* __restrict__ We, const float* __restrict__ ae_,
    float* __restrict__ v_edge) {
  int t = threadIdx.x;
  int d = t >> 2, hh = t & 3;
  float s3 = 0.f;
  for (int c = 0; c < CC; ++c) s3 += We[d * HC + hh * CC + c] * ae_[hh * CC + c];
  v_edge[t] = s3;
}

// K1: x16[n][c][h] = bf16 of x[n][h][c] (transposed for k_gat's ushort4/lane
// gather) FUSED with per-node logits a_src/a_dst (wave shuffle reduction on
// the fp32 acc, matching reference numerics).
__global__ __launch_bounds__(256) void k_xproj(
    const float* __restrict__ node, const float* __restrict__ W,
    const float* __restrict__ att_src, const float* __restrict__ att_dst,
    unsigned short* __restrict__ x16, float* __restrict__ a_src,
    float* __restrict__ a_dst) {
  __shared__ unsigned short tile[HC];
  int lane = threadIdx.x & 63;   // = c
  int wid = threadIdx.x >> 6;    // = h
  int t = threadIdx.x;
  float wcol[CC];
#pragma unroll
  for (int k = 0; k < CC; ++k) wcol[k] = W[k * HC + wid * 64 + lane];
  float asw = att_src[wid * 64 + lane];
  float adw = att_dst[wid * 64 + lane];
  for (int n = blockIdx.x; n < NN; n += gridDim.x) {
    float nval = node[n * CC + lane];
    float acc = 0.f;
#pragma unroll
    for (int k = 0; k < CC; ++k) {
      float s = __uint_as_float(__builtin_amdgcn_readlane(__float_as_uint(nval), k));
      acc += s * wcol[k];
    }
    float rs = acc * asw, rd = acc * adw;
#pragma unroll
    for (int s = 32; s; s >>= 1) {
      rs += __shfl_xor(rs, s);
      rd += __shfl_xor(rd, s);
    }
    if (lane == 0) {
      a_src[n * 4 + wid] = rs;
      a_dst[n * 4 + wid] = rd;
    }
    tile[lane * 4 + wid] = f2bf(acc);   // [c][h]
    __syncthreads();
    x16[(size_t)n * HC + t] = tile[t];
    __syncthreads();
  }
}

// K2: dst histogram.
__global__ __launch_bounds__(256) void k_hist(
    const int* __restrict__ ei, int* __restrict__ hist) {
  int e = blockIdx.x * 256 + threadIdx.x;
  if (e >= EE) return;
  atomicAdd(&hist[ei[EE + e]], 1);
}

// K3a: coalesced per-block sums of the histogram.
__global__ __launch_bounds__(256) void k_scanA(
    const int* __restrict__ hist, int* __restrict__ bsum) {
  __shared__ int s[256];
  int t = threadIdx.x;
  int idx = blockIdx.x * 256 + t;
  s[t] = (idx < NN) ? hist[idx] : 0;
  __syncthreads();
  for (int d = 128; d; d >>= 1) {
    if (t < d) s[t] += s[t + d];
    __syncthreads();
  }
  if (t == 0) bsum[blockIdx.x] = s[0];
}

// K3b: single block: exclusive scan of NB block sums.
__global__ __launch_bounds__(256) void k_scanB(
    const int* __restrict__ bsum, int* __restrict__ boff,
    int* __restrict__ ptr) {
  __shared__ int s[256];
  int t = threadIdx.x;
  int v = (t < NB) ? bsum[t] : 0;
  s[t] = v;
  __syncthreads();
  for (int d = 1; d < 256; d <<= 1) {
    int u = (t >= d) ? s[t - d] : 0;
    __syncthreads();
    s[t] += u;
    __syncthreads();
  }
  if (t < NB) boff[t] = s[t] - v;
  if (t == 255) ptr[NN] = s[255];
}

// K3c: per-block exclusive scan + block offset -> ptr, cursor.
__global__ __launch_bounds__(256) void k_scanC(
    const int* __restrict__ hist, const int* __restrict__ boff,
    int* __restrict__ ptr, int* __restrict__ cursor) {
  __shared__ int s[256];
  int t = threadIdx.x;
  int idx = blockIdx.x * 256 + t;
  int v = (idx < NN) ? hist[idx] : 0;
  s[t] = v;
  __syncthreads();
  for (int d = 1; d < 256; d <<= 1) {
    int u = (t >= d) ? s[t - d] : 0;
    __syncthreads();
    s[t] += u;
    __syncthreads();
  }
  if (idx < NN) {
    int p = boff[blockIdx.x] + s[t] - v;
    ptr[idx] = p;
    cursor[idx] = p;
  }
}

// K4: fused edge pass: t = exp(lrelu(a_src[sn]+a_dst[dn]+edge_attr@v)), then
// scatter ONE packed uint4 {bf16 t0..t3, sn, e} into the dst-sorted slot.
__global__ __launch_bounds__(256) void k_edge_perm(
    const float* __restrict__ edge_attr, const int* __restrict__ ei,
    const float* __restrict__ a_src, const float* __restrict__ a_dst,
    const float* __restrict__ v_edge, int* __restrict__ cursor,
    uint4* __restrict__ recs) {
  __shared__ float vs[DE * HH];
  int t = threadIdx.x;
  if (t < DE * HH) vs[t] = v_edge[t];
  __syncthreads();
  int e = blockIdx.x * 256 + t;
  if (e >= EE) return;
  const float4* ea4 = (const float4*)(edge_attr + (size_t)e * DE);
  float ae[4] = {0, 0, 0, 0};
#pragma unroll
  for (int dd = 0; dd < 4; ++dd) {
    float4 ev = ea4[dd];
    float evs[4] = {ev.x, ev.y, ev.z, ev.w};
#pragma unroll
    for (int j = 0; j < 4; ++j) {
      int d = dd * 4 + j;
#pragma unroll
      for (int h = 0; h < 4; ++h) ae[h] += evs[j] * vs[d * 4 + h];
    }
  }
  int sn = ei[e], dn = ei[EE + e];
  float4 as4 = *(const float4*)(a_src + (size_t)sn * 4);
  float4 ad4 = *(const float4*)(a_dst + (size_t)dn * 4);
  float t0 = __expf(lrelu(as4.x + ad4.x + ae[0]));
  float t1 = __expf(lrelu(as4.y + ad4.y + ae[1]));
  float t2 = __expf(lrelu(as4.z + ad4.z + ae[2]));
  float t3 = __expf(lrelu(as4.w + ad4.w + ae[3]));
  uint4 rec;
  rec.x = (unsigned int)f2bf(t0) | ((unsigned int)f2bf(t1) << 16);
  rec.y = (unsigned int)f2bf(t2) | ((unsigned int)f2bf(t3) << 16);
  rec.z = (unsigned int)sn;
  rec.w = (unsigned int)e;
  int pos = atomicAdd(&cursor[dn], 1);
  recs[pos] = rec;
}

// K5: one wave per dst node. Per edge: one 16B record bcast, one 8B/lane x16
// gather, 4 FMAs + 4 denom adds. Second lane-parallel loop writes att.
__global__ __launch_bounds__(256) void k_gat(
    const int* __restrict__ ptr, const uint4* __restrict__ recs,
    const unsigned short* __restrict__ x16, float* __restrict__ out_acc,
    float* __restrict__ att_out) {
  int lane = threadIdx.x & 63;
  int w = threadIdx.x >> 6;
  int v = blockIdx.x * 4 + w;
  int start = ptr[v], end = ptr[v + 1];
  float d0 = 0.f, d1 = 0.f, d2 = 0.f, d3 = 0.f;
  float acc0 = 0.f, acc1 = 0.f, acc2 = 0.f, acc3 = 0.f;
#pragma unroll 2
  for (int j = start; j < end; ++j) {
    uint4 rec = recs[j];                       // wave-uniform broadcast
    float t0 = __uint_as_float(rec.x << 16);
    float t1 = __uint_as_float(rec.x & 0xffff0000u);
    float t2 = __uint_as_float(rec.y << 16);
    float t3 = __uint_as_float(rec.y & 0xffff0000u);
    uint2 u = *(const uint2*)(x16 + (size_t)rec.z * HC + lane * 4);
    d0 += t0; d1 += t1; d2 += t2; d3 += t3;
    acc0 += t0 * __uint_as_float(u.x << 16);
    acc1 += t1 * __uint_as_float(u.x & 0xffff0000u);
    acc2 += t2 * __uint_as_float(u.y << 16);
    acc3 += t3 * __uint_as_float(u.y & 0xffff0000u);
  }
  float r0 = 1.f / (d0 + 1e-16f), r1 = 1.f / (d1 + 1e-16f);
  float r2 = 1.f / (d2 + 1e-16f), r3 = 1.f / (d3 + 1e-16f);
  out_acc[(size_t)v * CC + lane] =
      0.25f * (r0 * acc0 + r1 * acc1 + r2 * acc2 + r3 * acc3);
  for (int j = start + lane; j < end; j += 64) {
    uint4 rec = recs[j];
    float t0 = __uint_as_float(rec.x << 16) * r0;
    float t1 = __uint_as_float(rec.x & 0xffff0000u) * r1;
    float t2 = __uint_as_float(rec.y << 16) * r2;
    float t3 = __uint_as_float(rec.y & 0xffff0000u) * r3;
    *(float4*)(att_out + (size_t)rec.w * 4) = make_float4(t0, t1, t2, t3);
  }
}

// K6: GraphNorm stats, one block per group (batch sorted -> contiguous runs).
__global__ __launch_bounds__(256) void k_stats(
    const int* __restrict__ batch, const float* __restrict__ out_acc,
    const float* __restrict__ bias, const float* __restrict__ gns,
    float* __restrict__ mean_s, float* __restrict__ istd) {
  int g = blockIdx.x;
  int lane = threadIdx.x & 63;
  int w = threadIdx.x >> 6;
  int lo = 0, hi = NN;
  while (lo < hi) {
    int mid = (lo + hi) >> 1;
    if (batch[mid] < g) lo = mid + 1; else hi = mid;
  }
  int start = lo;
  hi = NN;
  while (lo < hi) {
    int mid = (lo + hi) >> 1;
    if (batch[mid] < g + 1) lo = mid + 1; else hi = mid;
  }
  int end = lo;
  float b = bias[lane];
  float s1 = 0.f, s2 = 0.f;
  for (int n = start + w; n < end; n += 4) {
    float v = out_acc[(size_t)n * CC + lane] + b;
    s1 += v;
    s2 += v * v;
  }
  __shared__ float l1[4][64], l2[4][64];
  l1[w][lane] = s1;
  l2[w][lane] = s2;
  __syncthreads();
  if (w == 0) {
    s1 = l1[0][lane] + l1[1][lane] + l1[2][lane] + l1[3][lane];
    s2 = l2[0][lane] + l2[1][lane] + l2[2][lane] + l2[3][lane];
    float c = fmaxf((float)(end - start), 1.0f);
    float mean = s1 / c;
    float ms = mean * gns[lane];
    float var = s2 / c - 2.f * ms * mean + ms * ms;
    mean_s[g * CC + lane] = ms;
    istd[g * CC + lane] = rsqrtf(var + EPSV);
  }
}

// K7: normalize + affine + relu -> y
__global__ __launch_bounds__(256) void k_final(
    const int* __restrict__ batch, const float* __restrict__ out_acc,
    const float* __restrict__ bias, const float* __restrict__ mean_s,
    const float* __restrict__ istd, const float* __restrict__ gnw,
    const float* __restrict__ gnb, float* __restrict__ y) {
  int lane = threadIdx.x & 63;
  int n = blockIdx.x * 4 + (threadIdx.x >> 6);
  int g = batch[n];
  float v = out_acc[(size_t)n * CC + lane] + bias[lane];
  float o = (v - mean_s[g * CC + lane]) * istd[g * CC + lane];
  float r = gnw[lane] * o + gnb[lane];
  y[(size_t)n * CC + lane] = fmaxf(r, 0.0f);
}

extern "C" void kernel_launch(void* const* d_in, const int* in_sizes, int n_in,
                              void* d_out, int out_size, void* d_ws, size_t ws_size,
                              hipStream_t stream) {
  const float* node = (const float*)d_in[0];
  const int* ei = (const int*)d_in[1];
  const float* eatt = (const float*)d_in[2];
  const int* batch = (const int*)d_in[3];
  const float* W = (const float*)d_in[4];
  const float* We = (const float*)d_in[5];
  const float* att_src = (const float*)d_in[6];
  const float* att_dst = (const float*)d_in[7];
  const float* att_edge = (const float*)d_in[8];
  const float* bias = (const float*)d_in[9];
  const float* gnw = (const float*)d_in[10];
  const float* gnb = (const float*)d_in[11];
  const float* gns = (const float*)d_in[12];

  float* ws = (float*)d_ws;
  size_t off = 0;
  uint4* recs = (uint4*)(ws + off);  off += (size_t)EE * 4;  // 12.8 MB
  float* a_src = ws + off;    off += (size_t)NN * HH;
  float* a_dst = ws + off;    off += (size_t)NN * HH;
  float* v_edge = ws + off;   off += 64;
  float* mean_s = ws + off;   off += GG * CC;
  float* istd = ws + off;     off += GG * CC;
  float* out_acc = ws + off;  off += (size_t)NN * CC;
  unsigned short* x16 = (unsigned short*)(ws + off);
  off += (size_t)NN * HC / 2;                           // 12.8M ushort
  int* iws = (int*)(ws + off);
  size_t ioff = 0;
  int* hist = iws + ioff;     ioff += NN;
  int* ptr = iws + ioff;      ioff += NN + 1;
  int* cursor = iws + ioff;   ioff += NN;
  int* bsum = iws + ioff;     ioff += NB;
  int* boff = iws + ioff;     ioff += NB;

  hipMemsetAsync(hist, 0, NN * sizeof(int), stream);

  float* y_out = (float*)d_out;
  float* att_out = (float*)d_out + (size_t)NN * CC;

  k_prep<<<1, 64, 0, stream>>>(We, att_edge, v_edge);
  k_hist<<<(EE + 255) / 256, 256, 0, stream>>>(ei, hist);
  k_xproj<<<2048, 256, 0, stream>>>(node, W, att_src, att_dst, x16, a_src,
                                    a_dst);
  k_scanA<<<NB, 256, 0, stream>>>(hist, bsum);
  k_scanB<<<1, 256, 0, stream>>>(bsum, boff, ptr);
  k_scanC<<<NB, 256, 0, stream>>>(hist, boff, ptr, cursor);
  k_edge_perm<<<(EE + 255) / 256, 256, 0, stream>>>(eatt, ei, a_src, a_dst,
                                                    v_edge, cursor, recs);
  k_gat<<<NN / 4, 256, 0, stream>>>(ptr, recs, x16, out_acc, att_out);
  k_stats<<<GG, 256, 0, stream>>>(batch, out_acc, bias, gns, mean_s, istd);
  k_final<<<NN / 4, 256, 0, stream>>>(batch, out_acc, bias, mean_s, istd, gnw,
                                      gnb, y_out);
}

// Round 7
// 407.684 us; speedup vs baseline: 1.1096x; 1.0317x over previous
//
#include <hip/hip_runtime.h>
#include <math.h>

#define NN 50000
#define EE 800000
#define HH 4
#define CC 64
#define DE 16
#define GG 64
#define HC 256          // H*C
#define NEG 0.2f
#define EPSV 1e-5f
#define NB 196          // scan blocks: 196*256 = 50176 >= NN
#define XB 2048         // xproj grid

__device__ __forceinline__ unsigned short f2bf(float f) {
  unsigned int x = __float_as_uint(f);
  unsigned int r = (x + 0x7fff + ((x >> 16) & 1)) >> 16;  // round-nearest-even
  return (unsigned short)r;
}
__device__ __forceinline__ float lrelu(float a) {
  return fmaxf(a, 0.f) + NEG * fminf(a, 0.f);
}

// K0: fold attention vectors through the projections.
// u_src[k][h] = sum_c W[k][h*C+c] * att_src[h][c]   (layout [k*4+h])
// v_edge[d][h] = sum_c We[d][h*C+c] * att_edge[h][c]
__global__ __launch_bounds__(256) void k_prep(
    const float* __restrict__ W, const float* __restrict__ We,
    const float* __restrict__ as_, const float* __restrict__ ad_,
    const float* __restrict__ ae_,
    float* __restrict__ u_src, float* __restrict__ u_dst,
    float* __restrict__ v_edge) {
  int t = threadIdx.x;
  int k = t >> 2, h = t & 3;
  float s1 = 0.f, s2 = 0.f;
  for (int c = 0; c < CC; ++c) {
    float w = W[k * HC + h * CC + c];
    s1 += w * as_[h * CC + c];
    s2 += w * ad_[h * CC + c];
  }
  u_src[t] = s1;
  u_dst[t] = s2;
  if (t < DE * HH) {
    int d = t >> 2, hh = t & 3;
    float s3 = 0.f;
    for (int c = 0; c < CC; ++c) s3 += We[d * HC + hh * CC + c] * ae_[hh * CC + c];
    v_edge[t] = s3;
  }
}

// K1: fused dst-histogram + projection.
// Thread t computes output (h = t&3, c = t>>2) so the [n][c][h] bf16 layout
// falls out of the indexing: x16[n*256 + t]. No LDS, no barriers, no shuffles.
__global__ __launch_bounds__(256) void k_xproj(
    const float* __restrict__ node, const float* __restrict__ W,
    const int* __restrict__ ei, int* __restrict__ hist,
    unsigned short* __restrict__ x16) {
  int t = threadIdx.x;
  // histogram portion (independent; overlaps with VALU-bound projection)
  for (int e = blockIdx.x * 256 + t; e < EE; e += XB * 256)
    atomicAdd(&hist[ei[EE + e]], 1);
  int lane = t & 63;
  int h = t & 3, c = t >> 2;
  float wcol[CC];
#pragma unroll
  for (int k = 0; k < CC; ++k) wcol[k] = W[k * HC + h * 64 + c];
  for (int n = blockIdx.x; n < NN; n += XB) {
    float nval = node[n * CC + lane];
    float acc = 0.f;
#pragma unroll
    for (int k = 0; k < CC; ++k) {
      float s = __uint_as_float(__builtin_amdgcn_readlane(__float_as_uint(nval), k));
      acc += s * wcol[k];
    }
    x16[(size_t)n * HC + t] = f2bf(acc);
  }
}

// K1b: per-node attention logits via the folded u mats (fp32, cheap).
__global__ __launch_bounds__(256) void k_attn_node(
    const float* __restrict__ node, const float* __restrict__ u_src,
    const float* __restrict__ u_dst, float* __restrict__ a_src,
    float* __restrict__ a_dst) {
  __shared__ float us[HC], ud[HC];
  int t = threadIdx.x;
  us[t] = u_src[t];
  ud[t] = u_dst[t];
  __syncthreads();
  int n = blockIdx.x * 256 + t;
  if (n >= NN) return;
  const float4* n4 = (const float4*)(node + n * CC);
  float aS[4] = {0, 0, 0, 0}, aD[4] = {0, 0, 0, 0};
#pragma unroll
  for (int kk = 0; kk < 16; ++kk) {
    float4 nv = n4[kk];
    float nvs[4] = {nv.x, nv.y, nv.z, nv.w};
#pragma unroll
    for (int j = 0; j < 4; ++j) {
      int k = kk * 4 + j;
#pragma unroll
      for (int h = 0; h < 4; ++h) {
        aS[h] += nvs[j] * us[k * 4 + h];
        aD[h] += nvs[j] * ud[k * 4 + h];
      }
    }
  }
  *(float4*)(a_src + n * 4) = make_float4(aS[0], aS[1], aS[2], aS[3]);
  *(float4*)(a_dst + n * 4) = make_float4(aD[0], aD[1], aD[2], aD[3]);
}

// K3a: coalesced per-block sums of the histogram.
__global__ __launch_bounds__(256) void k_scanA(
    const int* __restrict__ hist, int* __restrict__ bsum) {
  __shared__ int s[256];
  int t = threadIdx.x;
  int idx = blockIdx.x * 256 + t;
  s[t] = (idx < NN) ? hist[idx] : 0;
  __syncthreads();
  for (int d = 128; d; d >>= 1) {
    if (t < d) s[t] += s[t + d];
    __syncthreads();
  }
  if (t == 0) bsum[blockIdx.x] = s[0];
}

// K3b: single block: exclusive scan of NB block sums.
__global__ __launch_bounds__(256) void k_scanB(
    const int* __restrict__ bsum, int* __restrict__ boff,
    int* __restrict__ ptr) {
  __shared__ int s[256];
  int t = threadIdx.x;
  int v = (t < NB) ? bsum[t] : 0;
  s[t] = v;
  __syncthreads();
  for (int d = 1; d < 256; d <<= 1) {
    int u = (t >= d) ? s[t - d] : 0;
    __syncthreads();
    s[t] += u;
    __syncthreads();
  }
  if (t < NB) boff[t] = s[t] - v;
  if (t == 255) ptr[NN] = s[255];
}

// K3c: per-block exclusive scan + block offset -> ptr, cursor.
__global__ __launch_bounds__(256) void k_scanC(
    const int* __restrict__ hist, const int* __restrict__ boff,
    int* __restrict__ ptr, int* __restrict__ cursor) {
  __shared__ int s[256];
  int t = threadIdx.x;
  int idx = blockIdx.x * 256 + t;
  int v = (idx < NN) ? hist[idx] : 0;
  s[t] = v;
  __syncthreads();
  for (int d = 1; d < 256; d <<= 1) {
    int u = (t >= d) ? s[t - d] : 0;
    __syncthreads();
    s[t] += u;
    __syncthreads();
  }
  if (idx < NN) {
    int p = boff[blockIdx.x] + s[t] - v;
    ptr[idx] = p;
    cursor[idx] = p;
  }
}

// K4: fused edge pass: t = exp(lrelu(a_src[sn]+a_dst[dn]+edge_attr@v)), then
// scatter ONE packed uint4 {bf16 t0..t3, sn, e} into the dst-sorted slot.
__global__ __launch_bounds__(256) void k_edge_perm(
    const float* __restrict__ edge_attr, const int* __restrict__ ei,
    const float* __restrict__ a_src, const float* __restrict__ a_dst,
    const float* __restrict__ v_edge, int* __restrict__ cursor,
    uint4* __restrict__ recs) {
  __shared__ float vs[DE * HH];
  int t = threadIdx.x;
  if (t < DE * HH) vs[t] = v_edge[t];
  __syncthreads();
  int e = blockIdx.x * 256 + t;
  if (e >= EE) return;
  const float4* ea4 = (const float4*)(edge_attr + (size_t)e * DE);
  float ae[4] = {0, 0, 0, 0};
#pragma unroll
  for (int dd = 0; dd < 4; ++dd) {
    float4 ev = ea4[dd];
    float evs[4] = {ev.x, ev.y, ev.z, ev.w};
#pragma unroll
    for (int j = 0; j < 4; ++j) {
      int d = dd * 4 + j;
#pragma unroll
      for (int h = 0; h < 4; ++h) ae[h] += evs[j] * vs[d * 4 + h];
    }
  }
  int sn = ei[e], dn = ei[EE + e];
  float4 as4 = *(const float4*)(a_src + (size_t)sn * 4);
  float4 ad4 = *(const float4*)(a_dst + (size_t)dn * 4);
  float t0 = __expf(lrelu(as4.x + ad4.x + ae[0]));
  float t1 = __expf(lrelu(as4.y + ad4.y + ae[1]));
  float t2 = __expf(lrelu(as4.z + ad4.z + ae[2]));
  float t3 = __expf(lrelu(as4.w + ad4.w + ae[3]));
  uint4 rec;
  rec.x = (unsigned int)f2bf(t0) | ((unsigned int)f2bf(t1) << 16);
  rec.y = (unsigned int)f2bf(t2) | ((unsigned int)f2bf(t3) << 16);
  rec.z = (unsigned int)sn;
  rec.w = (unsigned int)e;
  int pos = atomicAdd(&cursor[dn], 1);
  recs[pos] = rec;
}

// K5: one wave per dst node. Per edge: one 16B record bcast, one 8B/lane x16
// gather, 4 FMAs + 4 denom adds. Second lane-parallel loop writes att.
__global__ __launch_bounds__(256) void k_gat(
    const int* __restrict__ ptr, const uint4* __restrict__ recs,
    const unsigned short* __restrict__ x16, float* __restrict__ out_acc,
    float* __restrict__ att_out) {
  int lane = threadIdx.x & 63;
  int w = threadIdx.x >> 6;
  int v = blockIdx.x * 4 + w;
  int start = ptr[v], end = ptr[v + 1];
  float d0 = 0.f, d1 = 0.f, d2 = 0.f, d3 = 0.f;
  float acc0 = 0.f, acc1 = 0.f, acc2 = 0.f, acc3 = 0.f;
#pragma unroll 2
  for (int j = start; j < end; ++j) {
    uint4 rec = recs[j];                       // wave-uniform broadcast
    float t0 = __uint_as_float(rec.x << 16);
    float t1 = __uint_as_float(rec.x & 0xffff0000u);
    float t2 = __uint_as_float(rec.y << 16);
    float t3 = __uint_as_float(rec.y & 0xffff0000u);
    uint2 u = *(const uint2*)(x16 + (size_t)rec.z * HC + lane * 4);
    d0 += t0; d1 += t1; d2 += t2; d3 += t3;
    acc0 += t0 * __uint_as_float(u.x << 16);
    acc1 += t1 * __uint_as_float(u.x & 0xffff0000u);
    acc2 += t2 * __uint_as_float(u.y << 16);
    acc3 += t3 * __uint_as_float(u.y & 0xffff0000u);
  }
  float r0 = 1.f / (d0 + 1e-16f), r1 = 1.f / (d1 + 1e-16f);
  float r2 = 1.f / (d2 + 1e-16f), r3 = 1.f / (d3 + 1e-16f);
  out_acc[(size_t)v * CC + lane] =
      0.25f * (r0 * acc0 + r1 * acc1 + r2 * acc2 + r3 * acc3);
  for (int j = start + lane; j < end; j += 64) {
    uint4 rec = recs[j];
    float t0 = __uint_as_float(rec.x << 16) * r0;
    float t1 = __uint_as_float(rec.x & 0xffff0000u) * r1;
    float t2 = __uint_as_float(rec.y << 16) * r2;
    float t3 = __uint_as_float(rec.y & 0xffff0000u) * r3;
    *(float4*)(att_out + (size_t)rec.w * 4) = make_float4(t0, t1, t2, t3);
  }
}

// K6: GraphNorm stats, one block per group (batch sorted -> contiguous runs).
__global__ __launch_bounds__(256) void k_stats(
    const int* __restrict__ batch, const float* __restrict__ out_acc,
    const float* __restrict__ bias, const float* __restrict__ gns,
    float* __restrict__ mean_s, float* __restrict__ istd) {
  int g = blockIdx.x;
  int lane = threadIdx.x & 63;
  int w = threadIdx.x >> 6;
  int lo = 0, hi = NN;
  while (lo < hi) {
    int mid = (lo + hi) >> 1;
    if (batch[mid] < g) lo = mid + 1; else hi = mid;
  }
  int start = lo;
  hi = NN;
  while (lo < hi) {
    int mid = (lo + hi) >> 1;
    if (batch[mid] < g + 1) lo = mid + 1; else hi = mid;
  }
  int end = lo;
  float b = bias[lane];
  float s1 = 0.f, s2 = 0.f;
  for (int n = start + w; n < end; n += 4) {
    float v = out_acc[(size_t)n * CC + lane] + b;
    s1 += v;
    s2 += v * v;
  }
  __shared__ float l1[4][64], l2[4][64];
  l1[w][lane] = s1;
  l2[w][lane] = s2;
  __syncthreads();
  if (w == 0) {
    s1 = l1[0][lane] + l1[1][lane] + l1[2][lane] + l1[3][lane];
    s2 = l2[0][lane] + l2[1][lane] + l2[2][lane] + l2[3][lane];
    float c = fmaxf((float)(end - start), 1.0f);
    float mean = s1 / c;
    float ms = mean * gns[lane];
    float var = s2 / c - 2.f * ms * mean + ms * ms;
    mean_s[g * CC + lane] = ms;
    istd[g * CC + lane] = rsqrtf(var + EPSV);
  }
}

// K7: normalize + affine + relu -> y
__global__ __launch_bounds__(256) void k_final(
    const int* __restrict__ batch, const float* __restrict__ out_acc,
    const float* __restrict__ bias, const float* __restrict__ mean_s,
    const float* __restrict__ istd, const float* __restrict__ gnw,
    const float* __restrict__ gnb, float* __restrict__ y) {
  int lane = threadIdx.x & 63;
  int n = blockIdx.x * 4 + (threadIdx.x >> 6);
  int g = batch[n];
  float v = out_acc[(size_t)n * CC + lane] + bias[lane];
  float o = (v - mean_s[g * CC + lane]) * istd[g * CC + lane];
  float r = gnw[lane] * o + gnb[lane];
  y[(size_t)n * CC + lane] = fmaxf(r, 0.0f);
}

extern "C" void kernel_launch(void* const* d_in, const int* in_sizes, int n_in,
                              void* d_out, int out_size, void* d_ws, size_t ws_size,
                              hipStream_t stream) {
  const float* node = (const float*)d_in[0];
  const int* ei = (const int*)d_in[1];
  const float* eatt = (const float*)d_in[2];
  const int* batch = (const int*)d_in[3];
  const float* W = (const float*)d_in[4];
  const float* We = (const float*)d_in[5];
  const float* att_src = (const float*)d_in[6];
  const float* att_dst = (const float*)d_in[7];
  const float* att_edge = (const float*)d_in[8];
  const float* bias = (const float*)d_in[9];
  const float* gnw = (const float*)d_in[10];
  const float* gnb = (const float*)d_in[11];
  const float* gns = (const float*)d_in[12];

  float* ws = (float*)d_ws;
  size_t off = 0;
  uint4* recs = (uint4*)(ws + off);  off += (size_t)EE * 4;  // 12.8 MB
  float* a_src = ws + off;    off += (size_t)NN * HH;
  float* a_dst = ws + off;    off += (size_t)NN * HH;
  float* u_src = ws + off;    off += HC;
  float* u_dst = ws + off;    off += HC;
  float* v_edge = ws + off;   off += 64;
  float* mean_s = ws + off;   off += GG * CC;
  float* istd = ws + off;     off += GG * CC;
  float* out_acc = ws + off;  off += (size_t)NN * CC;
  unsigned short* x16 = (unsigned short*)(ws + off);
  off += (size_t)NN * HC / 2;                           // 12.8M ushort
  int* iws = (int*)(ws + off);
  size_t ioff = 0;
  int* hist = iws + ioff;     ioff += NN;
  int* ptr = iws + ioff;      ioff += NN + 1;
  int* cursor = iws + ioff;   ioff += NN;
  int* bsum = iws + ioff;     ioff += NB;
  int* boff = iws + ioff;     ioff += NB;

  hipMemsetAsync(hist, 0, NN * sizeof(int), stream);

  float* y_out = (float*)d_out;
  float* att_out = (float*)d_out + (size_t)NN * CC;

  k_prep<<<1, 256, 0, stream>>>(W, We, att_src, att_dst, att_edge, u_src, u_dst,
                                v_edge);
  k_attn_node<<<(NN + 255) / 256, 256, 0, stream>>>(node, u_src, u_dst, a_src,
                                                    a_dst);
  k_xproj<<<XB, 256, 0, stream>>>(node, W, ei, hist, x16);
  k_scanA<<<NB, 256, 0, stream>>>(hist, bsum);
  k_scanB<<<1, 256, 0, stream>>>(bsum, boff, ptr);
  k_scanC<<<NB, 256, 0, stream>>>(hist, boff, ptr, cursor);
  k_edge_perm<<<(EE + 255) / 256, 256, 0, stream>>>(eatt, ei, a_src, a_dst,
                                                    v_edge, cursor, recs);
  k_gat<<<NN / 4, 256, 0, stream>>>(ptr, recs, x16, out_acc, att_out);
  k_stats<<<GG, 256, 0, stream>>>(batch, out_acc, bias, gns, mean_s, istd);
  k_final<<<NN / 4, 256, 0, stream>>>(batch, out_acc, bias, mean_s, istd, gnw,
                                      gnb, y_out);
}

// Round 8
// 372.188 us; speedup vs baseline: 1.2154x; 1.0954x over previous
//
#include <hip/hip_runtime.h>
#include <math.h>

#define NN 50000
#define EE 800000
#define HH 4
#define CC 64
#define DE 16
#define GG 64
#define HC 256          // H*C
#define NEG 0.2f
#define EPSV 1e-5f
#define NB 196          // scan blocks: 196*256 = 50176 >= NN

typedef __attribute__((ext_vector_type(8))) short short8;
typedef __attribute__((ext_vector_type(4))) float f32x4;

__device__ __forceinline__ unsigned short f2bf(float f) {
  unsigned int x = __float_as_uint(f);
  unsigned int r = (x + 0x7fff + ((x >> 16) & 1)) >> 16;  // round-nearest-even
  return (unsigned short)r;
}
__device__ __forceinline__ float lrelu(float a) {
  return fmaxf(a, 0.f) + NEG * fminf(a, 0.f);
}

// K0: blocks 0..63: Wb[k][t] = bf16(W[k][colmap(t)]), colmap(t)=(t&3)*64+(t>>2)
//     (so x16 = node @ Wb lands directly in [n][c][h] order).
//     block 64: v_edge[d][h] = sum_c We[d][h*C+c]*att_edge[h][c].
__global__ __launch_bounds__(256) void k_prep(
    const float* __restrict__ W, const float* __restrict__ We,
    const float* __restrict__ ae_, unsigned short* __restrict__ Wb,
    float* __restrict__ v_edge) {
  int b = blockIdx.x, t = threadIdx.x;
  if (b < 64) {
    Wb[b * HC + t] = f2bf(W[b * HC + (t & 3) * 64 + (t >> 2)]);
  } else if (t < DE * HH) {
    int d = t >> 2, h = t & 3;
    float s = 0.f;
    for (int c = 0; c < CC; ++c) s += We[d * HC + h * CC + c] * ae_[h * CC + c];
    v_edge[t] = s;
  }
}

// K1: MFMA projection. One block = 16 rows x 256 cols (4 waves x 4 col-tiles,
// 2 MFMAs each, K=64). Fused per-node logits a_src/a_dst from the fp32
// accumulator (shfl_xor + small LDS reduce). Verified gfx950 layouts:
// A[m=lane&15][k=quad*8+j], B[k=quad*8+j][n=lane&15], C col=lane&15,row=quad*4+r.
__global__ __launch_bounds__(256) void k_xproj(
    const float* __restrict__ node, const unsigned short* __restrict__ Wb,
    const float* __restrict__ att_src, const float* __restrict__ att_dst,
    unsigned short* __restrict__ x16, float* __restrict__ a_src,
    float* __restrict__ a_dst) {
  int lane = threadIdx.x & 63;
  int w = threadIdx.x >> 6;
  int m = lane & 15, quad = lane >> 4;
  int m0 = blockIdx.x * 16;
  const float* arow = node + (size_t)(m0 + m) * CC + quad * 8;
  float4 af0 = *(const float4*)(arow);
  float4 af1 = *(const float4*)(arow + 4);
  float4 af2 = *(const float4*)(arow + 32);
  float4 af3 = *(const float4*)(arow + 36);
  short8 a0 = {(short)f2bf(af0.x), (short)f2bf(af0.y), (short)f2bf(af0.z),
               (short)f2bf(af0.w), (short)f2bf(af1.x), (short)f2bf(af1.y),
               (short)f2bf(af1.z), (short)f2bf(af1.w)};
  short8 a1 = {(short)f2bf(af2.x), (short)f2bf(af2.y), (short)f2bf(af2.z),
               (short)f2bf(af2.w), (short)f2bf(af3.x), (short)f2bf(af3.y),
               (short)f2bf(af3.z), (short)f2bf(af3.w)};
  float sa[4] = {0, 0, 0, 0}, sd[4] = {0, 0, 0, 0};
#pragma unroll
  for (int i = 0; i < 4; ++i) {
    int t = (w * 4 + i) * 16 + m;
    short8 b0, b1;
#pragma unroll
    for (int j = 0; j < 8; ++j) {
      b0[j] = (short)Wb[(quad * 8 + j) * HC + t];
      b1[j] = (short)Wb[(32 + quad * 8 + j) * HC + t];
    }
    f32x4 acc = {0.f, 0.f, 0.f, 0.f};
    acc = __builtin_amdgcn_mfma_f32_16x16x32_bf16(a0, b0, acc, 0, 0, 0);
    acc = __builtin_amdgcn_mfma_f32_16x16x32_bf16(a1, b1, acc, 0, 0, 0);
    float us_t = att_src[(t & 3) * CC + (t >> 2)];
    float ud_t = att_dst[(t & 3) * CC + (t >> 2)];
#pragma unroll
    for (int r = 0; r < 4; ++r) {
      x16[(size_t)(m0 + quad * 4 + r) * HC + t] = f2bf(acc[r]);
      sa[r] += acc[r] * us_t;
      sd[r] += acc[r] * ud_t;
    }
  }
  __shared__ float lss[4][16][4], lsd[4][16][4];
#pragma unroll
  for (int r = 0; r < 4; ++r) {
    sa[r] += __shfl_xor(sa[r], 4);
    sa[r] += __shfl_xor(sa[r], 8);
    sd[r] += __shfl_xor(sd[r], 4);
    sd[r] += __shfl_xor(sd[r], 8);
  }
  if ((lane & 12) == 0) {
#pragma unroll
    for (int r = 0; r < 4; ++r) {
      lss[w][quad * 4 + r][lane & 3] = sa[r];
      lsd[w][quad * 4 + r][lane & 3] = sd[r];
    }
  }
  __syncthreads();
  int t = threadIdx.x;
  if (t < 64) {
    int row = t >> 2, h = t & 3;
    a_src[(size_t)(m0 + row) * 4 + h] =
        lss[0][row][h] + lss[1][row][h] + lss[2][row][h] + lss[3][row][h];
    a_dst[(size_t)(m0 + row) * 4 + h] =
        lsd[0][row][h] + lsd[1][row][h] + lsd[2][row][h] + lsd[3][row][h];
  }
}

// K2: dst histogram.
__global__ __launch_bounds__(256) void k_hist(
    const int* __restrict__ ei, int* __restrict__ hist) {
  int e = blockIdx.x * 256 + threadIdx.x;
  if (e >= EE) return;
  atomicAdd(&hist[ei[EE + e]], 1);
}

// K3a: coalesced per-block sums of the histogram.
__global__ __launch_bounds__(256) void k_scanA(
    const int* __restrict__ hist, int* __restrict__ bsum) {
  __shared__ int s[256];
  int t = threadIdx.x;
  int idx = blockIdx.x * 256 + t;
  s[t] = (idx < NN) ? hist[idx] : 0;
  __syncthreads();
  for (int d = 128; d; d >>= 1) {
    if (t < d) s[t] += s[t + d];
    __syncthreads();
  }
  if (t == 0) bsum[blockIdx.x] = s[0];
}

// K3b: single block: exclusive scan of NB block sums.
__global__ __launch_bounds__(256) void k_scanB(
    const int* __restrict__ bsum, int* __restrict__ boff,
    int* __restrict__ ptr) {
  __shared__ int s[256];
  int t = threadIdx.x;
  int v = (t < NB) ? bsum[t] : 0;
  s[t] = v;
  __syncthreads();
  for (int d = 1; d < 256; d <<= 1) {
    int u = (t >= d) ? s[t - d] : 0;
    __syncthreads();
    s[t] += u;
    __syncthreads();
  }
  if (t < NB) boff[t] = s[t] - v;
  if (t == 255) ptr[NN] = s[255];
}

// K3c: per-block exclusive scan + block offset -> ptr, cursor.
__global__ __launch_bounds__(256) void k_scanC(
    const int* __restrict__ hist, const int* __restrict__ boff,
    int* __restrict__ ptr, int* __restrict__ cursor) {
  __shared__ int s[256];
  int t = threadIdx.x;
  int idx = blockIdx.x * 256 + t;
  int v = (idx < NN) ? hist[idx] : 0;
  s[t] = v;
  __syncthreads();
  for (int d = 1; d < 256; d <<= 1) {
    int u = (t >= d) ? s[t - d] : 0;
    __syncthreads();
    s[t] += u;
    __syncthreads();
  }
  if (idx < NN) {
    int p = boff[blockIdx.x] + s[t] - v;
    ptr[idx] = p;
    cursor[idx] = p;
  }
}

// K4: fused edge pass: t = exp(lrelu(a_src[sn]+a_dst[dn]+edge_attr@v)), then
// scatter ONE packed uint4 {bf16 t0..t3, sn, e} into the dst-sorted slot.
__global__ __launch_bounds__(256) void k_edge_perm(
    const float* __restrict__ edge_attr, const int* __restrict__ ei,
    const float* __restrict__ a_src, const float* __restrict__ a_dst,
    const float* __restrict__ v_edge, int* __restrict__ cursor,
    uint4* __restrict__ recs) {
  __shared__ float vs[DE * HH];
  int t = threadIdx.x;
  if (t < DE * HH) vs[t] = v_edge[t];
  __syncthreads();
  int e = blockIdx.x * 256 + t;
  if (e >= EE) return;
  const float4* ea4 = (const float4*)(edge_attr + (size_t)e * DE);
  float ae[4] = {0, 0, 0, 0};
#pragma unroll
  for (int dd = 0; dd < 4; ++dd) {
    float4 ev = ea4[dd];
    float evs[4] = {ev.x, ev.y, ev.z, ev.w};
#pragma unroll
    for (int j = 0; j < 4; ++j) {
      int d = dd * 4 + j;
#pragma unroll
      for (int h = 0; h < 4; ++h) ae[h] += evs[j] * vs[d * 4 + h];
    }
  }
  int sn = ei[e], dn = ei[EE + e];
  float4 as4 = *(const float4*)(a_src + (size_t)sn * 4);
  float4 ad4 = *(const float4*)(a_dst + (size_t)dn * 4);
  float t0 = __expf(lrelu(as4.x + ad4.x + ae[0]));
  float t1 = __expf(lrelu(as4.y + ad4.y + ae[1]));
  float t2 = __expf(lrelu(as4.z + ad4.z + ae[2]));
  float t3 = __expf(lrelu(as4.w + ad4.w + ae[3]));
  uint4 rec;
  rec.x = (unsigned int)f2bf(t0) | ((unsigned int)f2bf(t1) << 16);
  rec.y = (unsigned int)f2bf(t2) | ((unsigned int)f2bf(t3) << 16);
  rec.z = (unsigned int)sn;
  rec.w = (unsigned int)e;
  int pos = atomicAdd(&cursor[dn], 1);
  recs[pos] = rec;
}

// K5: one wave per dst node. Per edge: one 16B record bcast, one 8B/lane x16
// gather, 4 FMAs + 4 denom adds. Second lane-parallel loop writes att.
__global__ __launch_bounds__(256) void k_gat(
    const int* __restrict__ ptr, const uint4* __restrict__ recs,
    const unsigned short* __restrict__ x16, float* __restrict__ out_acc,
    float* __restrict__ att_out) {
  int lane = threadIdx.x & 63;
  int w = threadIdx.x >> 6;
  int v = blockIdx.x * 4 + w;
  int start = ptr[v], end = ptr[v + 1];
  float d0 = 0.f, d1 = 0.f, d2 = 0.f, d3 = 0.f;
  float acc0 = 0.f, acc1 = 0.f, acc2 = 0.f, acc3 = 0.f;
#pragma unroll 2
  for (int j = start; j < end; ++j) {
    uint4 rec = recs[j];                       // wave-uniform broadcast
    float t0 = __uint_as_float(rec.x << 16);
    float t1 = __uint_as_float(rec.x & 0xffff0000u);
    float t2 = __uint_as_float(rec.y << 16);
    float t3 = __uint_as_float(rec.y & 0xffff0000u);
    uint2 u = *(const uint2*)(x16 + (size_t)rec.z * HC + lane * 4);
    d0 += t0; d1 += t1; d2 += t2; d3 += t3;
    acc0 += t0 * __uint_as_float(u.x << 16);
    acc1 += t1 * __uint_as_float(u.x & 0xffff0000u);
    acc2 += t2 * __uint_as_float(u.y << 16);
    acc3 += t3 * __uint_as_float(u.y & 0xffff0000u);
  }
  float r0 = 1.f / (d0 + 1e-16f), r1 = 1.f / (d1 + 1e-16f);
  float r2 = 1.f / (d2 + 1e-16f), r3 = 1.f / (d3 + 1e-16f);
  out_acc[(size_t)v * CC + lane] =
      0.25f * (r0 * acc0 + r1 * acc1 + r2 * acc2 + r3 * acc3);
  for (int j = start + lane; j < end; j += 64) {
    uint4 rec = recs[j];
    float t0 = __uint_as_float(rec.x << 16) * r0;
    float t1 = __uint_as_float(rec.x & 0xffff0000u) * r1;
    float t2 = __uint_as_float(rec.y << 16) * r2;
    float t3 = __uint_as_float(rec.y & 0xffff0000u) * r3;
    *(float4*)(att_out + (size_t)rec.w * 4) = make_float4(t0, t1, t2, t3);
  }
}

// K6: GraphNorm stats, one block per group (batch sorted -> contiguous runs).
__global__ __launch_bounds__(256) void k_stats(
    const int* __restrict__ batch, const float* __restrict__ out_acc,
    const float* __restrict__ bias, const float* __restrict__ gns,
    float* __restrict__ mean_s, float* __restrict__ istd) {
  int g = blockIdx.x;
  int lane = threadIdx.x & 63;
  int w = threadIdx.x >> 6;
  int lo = 0, hi = NN;
  while (lo < hi) {
    int mid = (lo + hi) >> 1;
    if (batch[mid] < g) lo = mid + 1; else hi = mid;
  }
  int start = lo;
  hi = NN;
  while (lo < hi) {
    int mid = (lo + hi) >> 1;
    if (batch[mid] < g + 1) lo = mid + 1; else hi = mid;
  }
  int end = lo;
  float b = bias[lane];
  float s1 = 0.f, s2 = 0.f;
  for (int n = start + w; n < end; n += 4) {
    float v = out_acc[(size_t)n * CC + lane] + b;
    s1 += v;
    s2 += v * v;
  }
  __shared__ float l1[4][64], l2[4][64];
  l1[w][lane] = s1;
  l2[w][lane] = s2;
  __syncthreads();
  if (w == 0) {
    s1 = l1[0][lane] + l1[1][lane] + l1[2][lane] + l1[3][lane];
    s2 = l2[0][lane] + l2[1][lane] + l2[2][lane] + l2[3][lane];
    float c = fmaxf((float)(end - start), 1.0f);
    float mean = s1 / c;
    float ms = mean * gns[lane];
    float var = s2 / c - 2.f * ms * mean + ms * ms;
    mean_s[g * CC + lane] = ms;
    istd[g * CC + lane] = rsqrtf(var + EPSV);
  }
}

// K7: normalize + affine + relu -> y
__global__ __launch_bounds__(256) void k_final(
    const int* __restrict__ batch, const float* __restrict__ out_acc,
    const float* __restrict__ bias, const float* __restrict__ mean_s,
    const float* __restrict__ istd, const float* __restrict__ gnw,
    const float* __restrict__ gnb, float* __restrict__ y) {
  int lane = threadIdx.x & 63;
  int n = blockIdx.x * 4 + (threadIdx.x >> 6);
  int g = batch[n];
  float v = out_acc[(size_t)n * CC + lane] + bias[lane];
  float o = (v - mean_s[g * CC + lane]) * istd[g * CC + lane];
  float r = gnw[lane] * o + gnb[lane];
  y[(size_t)n * CC + lane] = fmaxf(r, 0.0f);
}

extern "C" void kernel_launch(void* const* d_in, const int* in_sizes, int n_in,
                              void* d_out, int out_size, void* d_ws, size_t ws_size,
                              hipStream_t stream) {
  const float* node = (const float*)d_in[0];
  const int* ei = (const int*)d_in[1];
  const float* eatt = (const float*)d_in[2];
  const int* batch = (const int*)d_in[3];
  const float* W = (const float*)d_in[4];
  const float* We = (const float*)d_in[5];
  const float* att_src = (const float*)d_in[6];
  const float* att_dst = (const float*)d_in[7];
  const float* att_edge = (const float*)d_in[8];
  const float* bias = (const float*)d_in[9];
  const float* gnw = (const float*)d_in[10];
  const float* gnb = (const float*)d_in[11];
  const float* gns = (const float*)d_in[12];

  float* ws = (float*)d_ws;
  size_t off = 0;
  uint4* recs = (uint4*)(ws + off);  off += (size_t)EE * 4;  // 12.8 MB
  float* a_src = ws + off;    off += (size_t)NN * HH;
  float* a_dst = ws + off;    off += (size_t)NN * HH;
  float* v_edge = ws + off;   off += 64;
  float* mean_s = ws + off;   off += GG * CC;
  float* istd = ws + off;     off += GG * CC;
  float* out_acc = ws + off;  off += (size_t)NN * CC;
  unsigned short* x16 = (unsigned short*)(ws + off);
  off += (size_t)NN * HC / 2;                           // 12.8M ushort
  unsigned short* Wb = (unsigned short*)(ws + off);
  off += (size_t)CC * HC / 2;                           // 16K ushort
  int* iws = (int*)(ws + off);
  size_t ioff = 0;
  int* hist = iws + ioff;     ioff += NN;
  int* ptr = iws + ioff;      ioff += NN + 1;
  int* cursor = iws + ioff;   ioff += NN;
  int* bsum = iws + ioff;     ioff += NB;
  int* boff = iws + ioff;     ioff += NB;

  hipMemsetAsync(hist, 0, NN * sizeof(int), stream);

  float* y_out = (float*)d_out;
  float* att_out = (float*)d_out + (size_t)NN * CC;

  k_prep<<<65, 256, 0, stream>>>(W, We, att_edge, Wb, v_edge);
  k_hist<<<(EE + 255) / 256, 256, 0, stream>>>(ei, hist);
  k_xproj<<<NN / 16, 256, 0, stream>>>(node, Wb, att_src, att_dst, x16, a_src,
                                       a_dst);
  k_scanA<<<NB, 256, 0, stream>>>(hist, bsum);
  k_scanB<<<1, 256, 0, stream>>>(bsum, boff, ptr);
  k_scanC<<<NB, 256, 0, stream>>>(hist, boff, ptr, cursor);
  k_edge_perm<<<(EE + 255) / 256, 256, 0, stream>>>(eatt, ei, a_src, a_dst,
                                                    v_edge, cursor, recs);
  k_gat<<<NN / 4, 256, 0, stream>>>(ptr, recs, x16, out_acc, att_out);
  k_stats<<<GG, 256, 0, stream>>>(batch, out_acc, bias, gns, mean_s, istd);
  k_final<<<NN / 4, 256, 0, stream>>>(batch, out_acc, bias, mean_s, istd, gnw,
                                      gnb, y_out);
}